// Round 3
// baseline (734.053 us; speedup 1.0000x reference)
//
#include <hip/hip_runtime.h>

// Problem constants (fixed by the reference setup)
#define NE     50000   // edges
#define KMAX   16
#define NSPH   16
#define EMB    64
#define INTERM 64
#define UOUT   128

// R1: 32 edges/block. R2: cap ks-loop unroll at 4 (kills the Sfrag scratch
// spill: WRITE_SIZE 209 MB -> 28 MB, VGPR_Count 64, no spill code).
// R3: __launch_bounds__(512, 8) — kernel already fits 64 VGPR + 32 KB LDS,
// which supports 4 blocks/CU (32 waves/CU); the old (512,4) declaration was
// artificially capping residency at 2 blocks/CU. Kernel is latency-bound
// (MfmaUtil 7.7%, VALUBusy 15%, HBM 8%, Occupancy 38%) -> double the waves
// available to hide the L2/LDS/barrier latency.
#define EPB    32      // edges per block
#define LPW    4       // edges per wave (8 waves)

typedef __attribute__((ext_vector_type(4))) float v4f;
typedef __attribute__((ext_vector_type(4))) short s4;
typedef __attribute__((ext_vector_type(8))) short s8;

__device__ inline unsigned short f2b(float x){
  union { float f; unsigned int u; } v; v.f = x;
  unsigned int r = v.u + 0x7FFFu + ((v.u >> 16) & 1u);   // RNE f32->bf16
  return (unsigned short)(r >> 16);
}

__device__ inline s4 cvt4(v4f v){
  s4 r;
  r.x = (short)f2b(v.x); r.y = (short)f2b(v.y);
  r.z = (short)f2b(v.z); r.w = (short)f2b(v.w);
  return r;
}

// ---- prep kernel 1: scatter (id_reduce, Kidx) -> slot map (edge*16+slot -> triplet or -1)
__global__ void scatter_map_kernel(const int* __restrict__ idr, const int* __restrict__ kidx,
                                   int* __restrict__ map, int n){
  int t = blockIdx.x * 256 + threadIdx.x;
  if (t < n) map[idr[t] * KMAX + kidx[t]] = t;
}

// ---- prep kernel 2: pack f32 weight[c][i][u] into bf16 MFMA-B layout Wb[k>>3][u][k&7]
// k = ic*1024 + hf*512 + il*32 + chalf,  i = ic*16+il, c = hf*32+chalf
__global__ void pack_w_kernel(const float* __restrict__ wgt, unsigned short* __restrict__ wb){
  int o = blockIdx.x * 256 + threadIdx.x;          // 64*64*128 = 524288 total
  int j  = o & 7;
  int rest = o >> 3;
  int u  = rest & 127;
  int kb = rest >> 7;
  int k  = kb * 8 + j;
  int ic = k >> 10, rem = k & 1023, hf = rem >> 9, r2 = rem & 511, il = r2 >> 5, ch = r2 & 31;
  int i = ic * 16 + il, c = hf * 32 + ch;
  wb[o] = f2b(wgt[c * (INTERM * UOUT) + i * UOUT + u]);
}

// ---- fused kernel: 32 edges/block, 8 waves. S in regs (C-layout==B-layout for K=16 MFMA),
// T goes MFMA -> (cvt) -> swizzled LDS directly, rbf A-frags cached per i-chunk,
// out accumulates in VGPRs. All fragment layouts identical to the 64-edge version.
__global__ __launch_bounds__(512, 8)   // 64-VGPR cap -> 4 blocks/CU (32 waves/CU)
void fused_kernel(const float* __restrict__ rbf,
                  const float* __restrict__ sph,
                  const float* __restrict__ m,
                  const unsigned short* __restrict__ wb,
                  const int* __restrict__ map,
                  float* __restrict__ out)
{
  __shared__ __align__(16) unsigned short Tlds[EPB * 512];   // 32 KB
  const int tid = threadIdx.x;
  const int l = tid & 63;
  const int w = tid >> 6;       // wave 0..7
  const int q = l >> 4;         // quad 0..3
  const int h = l & 15;
  const int ebase = blockIdx.x * EPB;

  // ---------- phase 0: S = sph @ m2 for this wave's 4 edges; keep as B-frags (K=16) in regs
  s4 Sfrag[LPW][4];
#pragma unroll
  for (int le = 0; le < LPW; ++le){
    int e = ebase + w * LPW + le; if (e >= NE) e = NE - 1;
    // A-frag (sph): A[s=h][k=q*4+j] -> 16B contiguous f32 load, convert
    s4 a = cvt4(*reinterpret_cast<const v4f*>(sph + e * 256 + h * 16 + q * 4));
    int t0 = map[e * 16 + q * 4 + 0];
    int t1 = map[e * 16 + q * 4 + 1];
    int t2 = map[e * 16 + q * 4 + 2];
    int t3 = map[e * 16 + q * 4 + 3];
#pragma unroll
    for (int ct = 0; ct < 4; ++ct){
      int c = ct * 16 + h;
      // B-frag (m2 gather): B[k=q*4+j][n=c]
      s4 b;
      b.x = (t0 >= 0) ? (short)f2b(m[t0 * 64 + c]) : (short)0;
      b.y = (t1 >= 0) ? (short)f2b(m[t1 * 64 + c]) : (short)0;
      b.z = (t2 >= 0) ? (short)f2b(m[t2 * 64 + c]) : (short)0;
      b.w = (t3 >= 0) ? (short)f2b(m[t3 * 64 + c]) : (short)0;
      v4f acc = {0.f, 0.f, 0.f, 0.f};
      acc = __builtin_amdgcn_mfma_f32_16x16x16bf16_1k(a, b, acc, 0, 0, 0);
      // D[s=q*4+r][c=h] == B-frag[k=q*4+j][n=h]  -> direct reuse as next B operand
      Sfrag[le][ct] = cvt4(acc);
    }
  }

  v4f Oacc[2];
#pragma unroll
  for (int mt = 0; mt < 2; ++mt) Oacc[mt] = (v4f){0.f, 0.f, 0.f, 0.f};

#pragma unroll 1   // keep i-chunk loop rolled: I-cache
  for (int ic = 0; ic < 4; ++ic){
    // rbf A-frags for this i-chunk, cached across both hf passes (8 VGPRs)
    s4 Arbf[LPW];
#pragma unroll
    for (int le = 0; le < LPW; ++le){
      int e = ebase + w * LPW + le; if (e >= NE) e = NE - 1;
      Arbf[le] = cvt4(*reinterpret_cast<const v4f*>(rbf + e * 1024 + (ic * 16 + h) * 16 + q * 4));
    }
#pragma unroll
    for (int hf = 0; hf < 2; ++hf){
      // ---------- step 2+write: T[il][c-half] -> MFMA -> cvt -> swizzled LDS, no register block
#pragma unroll
      for (int le = 0; le < LPW; ++le){
        int row = w * LPW + le;
#pragma unroll
        for (int ct2 = 0; ct2 < 2; ++ct2){
          v4f acc = {0.f, 0.f, 0.f, 0.f};
          acc = __builtin_amdgcn_mfma_f32_16x16x16bf16_1k(Arbf[le], Sfrag[le][hf * 2 + ct2], acc, 0, 0, 0);
          s4 tv = cvt4(acc);   // T[il=q*4+r][c=(hf*2+ct2)*16+h]
#pragma unroll
          for (int r = 0; r < 4; ++r){
            int il = q * 4 + r;
            int kh = il * 32 + ct2 * 16 + h;
            int b  = kh >> 3;
            int bs = b ^ (row & 7) ^ (((b >> 4) & 3) << 1);
            Tlds[row * 512 + bs * 8 + (kh & 7)] = (unsigned short)tv[r];
          }
        }
      }
      __syncthreads();
      // ---------- step 3: out += T_half(32x512) @ Wb(512x128)
      // R2: unroll capped at 4 so only 4 bfr (16 VGPRs) are in flight at the
      // scheduling peak, instead of 16 (64 VGPRs) -> no Sfrag spill.
      const int kbase = ic * 1024 + hf * 512;
#pragma unroll 4
      for (int ks = 0; ks < 16; ++ks){
        int k0 = ks * 32;
        int bb = (k0 >> 3) + q;
        int bsw = bb ^ (h & 7) ^ (((bb >> 4) & 3) << 1);   // same for all mt (mt*16 % 8 == 0)
        // B-frag: B[k=q*8+j][u=w*16+h] from packed Wb
        int kb = (kbase + k0 + q * 8) >> 3;
        s8 bfr = *reinterpret_cast<const s8*>(wb + (kb * 128 + (w * 16 + h)) * 8);
#pragma unroll
        for (int mt = 0; mt < 2; ++mt){
          int row = mt * 16 + h;   // A-frag: A[edge=h][k contiguous 8]
          s8 afr = *reinterpret_cast<const s8*>(&Tlds[row * 512 + bsw * 8]);
          Oacc[mt] = __builtin_amdgcn_mfma_f32_16x16x32_bf16(afr, bfr, Oacc[mt], 0, 0, 0);
        }
      }
      __syncthreads();
    }
  }

  // ---------- epilogue: D[edge=q*4+r (within 16)][u=h], u-block = w*16; f32 out
#pragma unroll
  for (int mt = 0; mt < 2; ++mt){
#pragma unroll
    for (int r = 0; r < 4; ++r){
      int e = ebase + mt * 16 + q * 4 + r;
      if (e < NE) out[e * 128 + w * 16 + h] = Oacc[mt][r];
    }
  }
}

extern "C" void kernel_launch(void* const* d_in, const int* in_sizes, int n_in,
                              void* d_out, int out_size, void* d_ws, size_t ws_size,
                              hipStream_t stream) {
  const float* rbf = (const float*)d_in[0];   // (NE, 64, 16) f32
  const float* sph = (const float*)d_in[1];   // (NE, 16, 16) f32
  const float* m   = (const float*)d_in[2];   // (400000, 64) f32
  const float* wgt = (const float*)d_in[3];   // (64, 64, 128) f32
  const int* idr  = (const int*)d_in[4];      // (400000,) int32
  const int* kidx = (const int*)d_in[5];      // (400000,) int32
  float* out = (float*)d_out;                 // (NE, 128) f32

  const int nTrip = in_sizes[4];
  int*            map = (int*)d_ws;                                   // NE*16 int32 = 3.2 MB
  unsigned short* wb  = (unsigned short*)((char*)d_ws + (size_t)NE * 16 * 4); // 1 MB packed bf16 weight

  hipMemsetAsync(map, 0xFF, (size_t)NE * 16 * 4, stream);             // all slots -> -1
  scatter_map_kernel<<<dim3((nTrip + 255) / 256), dim3(256), 0, stream>>>(idr, kidx, map, nTrip);
  pack_w_kernel<<<dim3((EMB * INTERM * UOUT) / 256), dim3(256), 0, stream>>>(wgt, wb);
  fused_kernel<<<dim3((NE + EPB - 1) / EPB), dim3(512), 0, stream>>>(rbf, sph, m, wb, map, out);
}

// Round 4
// 555.370 us; speedup vs baseline: 1.3217x; 1.3217x over previous
//
#include <hip/hip_runtime.h>

// Problem constants (fixed by the reference setup)
#define NE     50000   // edges
#define KMAX   16
#define NSPH   16
#define EMB    64
#define INTERM 64
#define UOUT   128

// R2: unroll-4 ks loop kills Sfrag spill (WRITE 209->28 MB). 357 us fused.
// R3 FAILED: (512,8) forced 32-VGPR cap -> spill returned (WRITE 281 MB). The
// kernel needs the full 128-reg budget of (512,4); occupancy is capped at
// 2 blocks/CU. Reverted.
// R4: attack the ~90% stall time directly:
//  - transposed step2 (mfma(Sfrag,Arbf) -> T^T tiles): lane holds 4 k-contiguous
//    T values -> single ds_write_b64 instead of 4 scalar ds_write_b16.
//  - merged hf halves: Tlds 64 KB, 8 barriers/block instead of 16.
//  - raw s_barrier + lgkmcnt(0) only (no vmcnt(0) drain) so global loads stay
//    in flight across barriers.
//  - software-pipelined bfr (next 4-ks chunk prefetched) + rbf ic+1 prefetch.
#define EPB    32      // edges per block
#define LPW    4       // edges per wave (8 waves)

typedef __attribute__((ext_vector_type(4))) float v4f;
typedef __attribute__((ext_vector_type(4))) short s4;
typedef __attribute__((ext_vector_type(8))) short s8;

__device__ inline unsigned short f2b(float x){
  union { float f; unsigned int u; } v; v.f = x;
  unsigned int r = v.u + 0x7FFFu + ((v.u >> 16) & 1u);   // RNE f32->bf16
  return (unsigned short)(r >> 16);
}

__device__ inline s4 cvt4(v4f v){
  s4 r;
  r.x = (short)f2b(v.x); r.y = (short)f2b(v.y);
  r.z = (short)f2b(v.z); r.w = (short)f2b(v.w);
  return r;
}

// workgroup barrier that does NOT drain vmcnt: LDS ordering only.
__device__ inline void lds_barrier(){
  asm volatile("s_waitcnt lgkmcnt(0)" ::: "memory");
  __builtin_amdgcn_s_barrier();
}

// ---- prep kernel 1: scatter (id_reduce, Kidx) -> slot map (edge*16+slot -> triplet or -1)
__global__ void scatter_map_kernel(const int* __restrict__ idr, const int* __restrict__ kidx,
                                   int* __restrict__ map, int n){
  int t = blockIdx.x * 256 + threadIdx.x;
  if (t < n) map[idr[t] * KMAX + kidx[t]] = t;
}

// ---- prep kernel 2: pack f32 weight[c][i][u] into bf16 MFMA-B layout Wb[k>>3][u][k&7]
// k = ic*1024 + hf*512 + il*32 + chalf,  i = ic*16+il, c = hf*32+chalf
__global__ void pack_w_kernel(const float* __restrict__ wgt, unsigned short* __restrict__ wb){
  int o = blockIdx.x * 256 + threadIdx.x;          // 64*64*128 = 524288 total
  int j  = o & 7;
  int rest = o >> 3;
  int u  = rest & 127;
  int kb = rest >> 7;
  int k  = kb * 8 + j;
  int ic = k >> 10, rem = k & 1023, hf = rem >> 9, r2 = rem & 511, il = r2 >> 5, ch = r2 & 31;
  int i = ic * 16 + il, c = hf * 32 + ch;
  wb[o] = f2b(wgt[c * (INTERM * UOUT) + i * UOUT + u]);
}

// ---- fused kernel: 32 edges/block, 8 waves.
__global__ __launch_bounds__(512, 4)   // full 128-VGPR budget, 2 blocks/CU
void fused_kernel(const float* __restrict__ rbf,
                  const float* __restrict__ sph,
                  const float* __restrict__ m,
                  const unsigned short* __restrict__ wb,
                  const int* __restrict__ map,
                  float* __restrict__ out)
{
  // 32 rows x 1024 shorts (one full ic slab: k' = hf*512 + il*32 + chalf) = 64 KB
  __shared__ __align__(16) unsigned short Tlds[EPB * 1024];
  const int tid = threadIdx.x;
  const int l = tid & 63;
  const int w = tid >> 6;       // wave 0..7
  const int q = l >> 4;         // quad 0..3
  const int h = l & 15;
  const int ebase = blockIdx.x * EPB;

  // ---------- phase 0: S = sph @ m2 for this wave's 4 edges; keep as B-frags (K=16) in regs
  s4 Sfrag[LPW][4];
#pragma unroll
  for (int le = 0; le < LPW; ++le){
    int e = ebase + w * LPW + le; if (e >= NE) e = NE - 1;
    // A-frag (sph): A[s=h][k=q*4+j] -> 16B contiguous f32 load, convert
    s4 a = cvt4(*reinterpret_cast<const v4f*>(sph + e * 256 + h * 16 + q * 4));
    int t0 = map[e * 16 + q * 4 + 0];
    int t1 = map[e * 16 + q * 4 + 1];
    int t2 = map[e * 16 + q * 4 + 2];
    int t3 = map[e * 16 + q * 4 + 3];
#pragma unroll
    for (int ct = 0; ct < 4; ++ct){
      int c = ct * 16 + h;
      // B-frag (m2 gather): B[k=q*4+j][n=c]
      s4 b;
      b.x = (t0 >= 0) ? (short)f2b(m[t0 * 64 + c]) : (short)0;
      b.y = (t1 >= 0) ? (short)f2b(m[t1 * 64 + c]) : (short)0;
      b.z = (t2 >= 0) ? (short)f2b(m[t2 * 64 + c]) : (short)0;
      b.w = (t3 >= 0) ? (short)f2b(m[t3 * 64 + c]) : (short)0;
      v4f acc = {0.f, 0.f, 0.f, 0.f};
      acc = __builtin_amdgcn_mfma_f32_16x16x16bf16_1k(a, b, acc, 0, 0, 0);
      // D[s=q*4+r][c=h] == B-frag[k=q*4+j][n=h]  -> direct reuse as next operand
      Sfrag[le][ct] = cvt4(acc);
    }
  }

  v4f Oacc[2];
#pragma unroll
  for (int mt = 0; mt < 2; ++mt) Oacc[mt] = (v4f){0.f, 0.f, 0.f, 0.f};

  // rbf raw frags for ic=0 (f32, converted at use; reloaded by prefetch each ic)
  v4f Araw[LPW];
#pragma unroll
  for (int le = 0; le < LPW; ++le){
    int e = ebase + w * LPW + le; if (e >= NE) e = NE - 1;
    Araw[le] = *reinterpret_cast<const v4f*>(rbf + (size_t)e * 1024 + h * 16 + q * 4);
  }

#pragma unroll 1   // keep i-chunk loop rolled: I-cache
  for (int ic = 0; ic < 4; ++ic){
    // ---------- step 2 (transposed): mfma(Sfrag, Arbf) -> D[c-rows][i-cols] = T^T tile.
    // lane(q,h) reg r = T[i=ic*16+h][c=ct*16+q*4+r] -> 4 k-contiguous values -> ds_write_b64.
#pragma unroll
    for (int le = 0; le < LPW; ++le){
      s4 Acvt = cvt4(Araw[le]);   // A-frag rbf: A[i=h][s=q*4+j] (as B-operand = rbf^T)
      int row = w * LPW + le;
#pragma unroll
      for (int ct = 0; ct < 4; ++ct){
        v4f acc = {0.f, 0.f, 0.f, 0.f};
        acc = __builtin_amdgcn_mfma_f32_16x16x16bf16_1k(Sfrag[le][ct], Acvt, acc, 0, 0, 0);
        s4 tv = cvt4(acc);
        // k' = (ct>>1)*512 + h*32 + (ct&1)*16 + q*4 + r ; 16B-block b = k'>>3
        int b  = (ct >> 1) * 64 + h * 4 + (ct & 1) * 2 + (q >> 1);
        int bs = b ^ (row & 7) ^ (((b >> 4) & 3) << 1);
        *reinterpret_cast<s4*>(&Tlds[row * 1024 + bs * 8 + (q & 1) * 4]) = tv;
      }
      // prefetch next ic's rbf frag; stays in flight across the raw barriers
      int icn = (ic < 3) ? ic + 1 : 3;
      int e = ebase + w * LPW + le; if (e >= NE) e = NE - 1;
      Araw[le] = *reinterpret_cast<const v4f*>(rbf + (size_t)e * 1024 + (icn * 16 + h) * 16 + q * 4);
    }
    lds_barrier();

    // ---------- step 3: out += T_ic(32x1024) @ Wb_ic(1024x128), software-pipelined bfr
    const unsigned short* wptr = wb + (size_t)ic * 131072 + (size_t)q * 1024 + (size_t)(w * 16 + h) * 8;
    s8 bf[4], nf[4];
#pragma unroll
    for (int j = 0; j < 4; ++j)
      bf[j] = *reinterpret_cast<const s8*>(wptr + j * 4096);
#pragma unroll 1
    for (int kc = 0; kc < 8; ++kc){
      const unsigned short* np = wptr + (size_t)((kc < 7) ? kc + 1 : 7) * 16384;
#pragma unroll
      for (int j = 0; j < 4; ++j)
        nf[j] = *reinterpret_cast<const s8*>(np + j * 4096);
#pragma unroll
      for (int j = 0; j < 4; ++j){
        int ks = kc * 4 + j;
        int bb = ks * 4 + q;
        int bsw = bb ^ (h & 7) ^ (((bb >> 4) & 3) << 1);   // same for both mt (row&7 == h&7)
        s8 afr0 = *reinterpret_cast<const s8*>(&Tlds[h * 1024 + bsw * 8]);
        s8 afr1 = *reinterpret_cast<const s8*>(&Tlds[(16 + h) * 1024 + bsw * 8]);
        Oacc[0] = __builtin_amdgcn_mfma_f32_16x16x32_bf16(afr0, bf[j], Oacc[0], 0, 0, 0);
        Oacc[1] = __builtin_amdgcn_mfma_f32_16x16x32_bf16(afr1, bf[j], Oacc[1], 0, 0, 0);
      }
#pragma unroll
      for (int j = 0; j < 4; ++j) bf[j] = nf[j];
    }
    lds_barrier();
  }

  // ---------- epilogue: D[edge=q*4+r (within 16)][u=h], u-block = w*16; f32 out
#pragma unroll
  for (int mt = 0; mt < 2; ++mt){
#pragma unroll
    for (int r = 0; r < 4; ++r){
      int e = ebase + mt * 16 + q * 4 + r;
      if (e < NE) out[e * 128 + w * 16 + h] = Oacc[mt][r];
    }
  }
}

extern "C" void kernel_launch(void* const* d_in, const int* in_sizes, int n_in,
                              void* d_out, int out_size, void* d_ws, size_t ws_size,
                              hipStream_t stream) {
  const float* rbf = (const float*)d_in[0];   // (NE, 64, 16) f32
  const float* sph = (const float*)d_in[1];   // (NE, 16, 16) f32
  const float* m   = (const float*)d_in[2];   // (400000, 64) f32
  const float* wgt = (const float*)d_in[3];   // (64, 64, 128) f32
  const int* idr  = (const int*)d_in[4];      // (400000,) int32
  const int* kidx = (const int*)d_in[5];      // (400000,) int32
  float* out = (float*)d_out;                 // (NE, 128) f32

  const int nTrip = in_sizes[4];
  int*            map = (int*)d_ws;                                   // NE*16 int32 = 3.2 MB
  unsigned short* wb  = (unsigned short*)((char*)d_ws + (size_t)NE * 16 * 4); // 1 MB packed bf16 weight

  hipMemsetAsync(map, 0xFF, (size_t)NE * 16 * 4, stream);             // all slots -> -1
  scatter_map_kernel<<<dim3((nTrip + 255) / 256), dim3(256), 0, stream>>>(idr, kidx, map, nTrip);
  pack_w_kernel<<<dim3((EMB * INTERM * UOUT) / 256), dim3(256), 0, stream>>>(wgt, wb);
  fused_kernel<<<dim3((NE + EPB - 1) / EPB), dim3(512), 0, stream>>>(rbf, sph, m, wb, map, out);
}

// Round 6
// 514.419 us; speedup vs baseline: 1.4270x; 1.0796x over previous
//
#include <hip/hip_runtime.h>

// Problem constants (fixed by the reference setup)
#define NE     50000   // edges
#define KMAX   16
#define NSPH   16
#define EMB    64
#define INTERM 64
#define UOUT   128

// R2: unroll-4 ks loop kills Sfrag spill. R3 FAILED: (512,8) -> 32-VGPR cap,
// spill returned; kernel needs (512,4)'s full budget, 2 blocks/CU max.
// R4: transposed step2 (ds_write_b64), merged hf (64KB Tlds, 8 barriers),
// lgkm-only barriers, pipelined bfr/rbf. 291 us fused.
// R5 FAILED (NaN): bundled inline-asm v_cvt_pk_bf16_f32 with the structural
// changes; the structural half (k-split, epilogue reduce, F-ring) verifies
// line-by-line, the hand-rolled asm does not -> suspected culprit.
// R6: R5 structure with cvt4 reverted to the bit-exact software f2b of R0-R4.
//   - step3 k-split: wave = (kq = w>>2) k-half x (uh = w&3) u32-slice ->
//     per-wave LDS reads halve (T word read 4x not 8x); pair-reduce the two
//     k-half partials through the freed Tlds in the epilogue.
//   - depth-4 bfr ring (32 VGPR in flight), rbf ic+1 prefetch.
#define EPB    32      // edges per block
#define LPW    4       // edges per wave (8 waves)

typedef __attribute__((ext_vector_type(4))) float v4f;
typedef __attribute__((ext_vector_type(4))) short s4;
typedef __attribute__((ext_vector_type(8))) short s8;

__device__ inline unsigned short f2b(float x){
  union { float f; unsigned int u; } v; v.f = x;
  unsigned int r = v.u + 0x7FFFu + ((v.u >> 16) & 1u);   // RNE f32->bf16
  return (unsigned short)(r >> 16);
}

__device__ inline s4 cvt4(v4f v){
  s4 r;
  r.x = (short)f2b(v.x); r.y = (short)f2b(v.y);
  r.z = (short)f2b(v.z); r.w = (short)f2b(v.w);
  return r;
}

// workgroup barrier that does NOT drain vmcnt: LDS ordering only.
__device__ inline void lds_barrier(){
  asm volatile("s_waitcnt lgkmcnt(0)" ::: "memory");
  __builtin_amdgcn_s_barrier();
}

// ---- prep kernel 1: scatter (id_reduce, Kidx) -> slot map (edge*16+slot -> triplet or -1)
__global__ void scatter_map_kernel(const int* __restrict__ idr, const int* __restrict__ kidx,
                                   int* __restrict__ map, int n){
  int t = blockIdx.x * 256 + threadIdx.x;
  if (t < n) map[idr[t] * KMAX + kidx[t]] = t;
}

// ---- prep kernel 2: pack f32 weight[c][i][u] into bf16 MFMA-B layout Wb[k>>3][u][k&7]
// k = ic*1024 + hf*512 + il*32 + chalf,  i = ic*16+il, c = hf*32+chalf
__global__ void pack_w_kernel(const float* __restrict__ wgt, unsigned short* __restrict__ wb){
  int o = blockIdx.x * 256 + threadIdx.x;          // 64*64*128 = 524288 total
  int j  = o & 7;
  int rest = o >> 3;
  int u  = rest & 127;
  int kb = rest >> 7;
  int k  = kb * 8 + j;
  int ic = k >> 10, rem = k & 1023, hf = rem >> 9, r2 = rem & 511, il = r2 >> 5, ch = r2 & 31;
  int i = ic * 16 + il, c = hf * 32 + ch;
  wb[o] = f2b(wgt[c * (INTERM * UOUT) + i * UOUT + u]);
}

// ---- fused kernel: 32 edges/block, 8 waves.
__global__ __launch_bounds__(512, 4)   // full 128-VGPR budget, 2 blocks/CU
void fused_kernel(const float* __restrict__ rbf,
                  const float* __restrict__ sph,
                  const float* __restrict__ m,
                  const unsigned short* __restrict__ wb,
                  const int* __restrict__ map,
                  float* __restrict__ out)
{
  // 32 rows x 1024 shorts (one full ic slab: k' = hf*512 + il*32 + chalf) = 64 KB
  __shared__ __align__(16) unsigned short Tlds[EPB * 1024];
  const int tid = threadIdx.x;
  const int l = tid & 63;
  const int w = tid >> 6;       // wave 0..7
  const int q = l >> 4;         // quad 0..3
  const int h = l & 15;
  const int ebase = blockIdx.x * EPB;
  // step3 wave roles: k-half and u32-slice
  const int kq = w >> 2;        // 0..1
  const int uh = w & 3;         // 0..3  (u = uh*32 .. +31)

  // ---------- phase 0: S = sph @ m2 for this wave's 4 edges; keep as B-frags (K=16) in regs
  s4 Sfrag[LPW][4];
#pragma unroll
  for (int le = 0; le < LPW; ++le){
    int e = ebase + w * LPW + le; if (e >= NE) e = NE - 1;
    // A-frag (sph): A[s=h][k=q*4+j] -> 16B contiguous f32 load, convert
    s4 a = cvt4(*reinterpret_cast<const v4f*>(sph + e * 256 + h * 16 + q * 4));
    int t0 = map[e * 16 + q * 4 + 0];
    int t1 = map[e * 16 + q * 4 + 1];
    int t2 = map[e * 16 + q * 4 + 2];
    int t3 = map[e * 16 + q * 4 + 3];
#pragma unroll
    for (int ct = 0; ct < 4; ++ct){
      int c = ct * 16 + h;
      // B-frag (m2 gather): B[k=q*4+j][n=c]; predicated f32 loads, then pack
      float fx = 0.f, fy = 0.f, fz = 0.f, fw = 0.f;
      if (t0 >= 0) fx = m[t0 * 64 + c];
      if (t1 >= 0) fy = m[t1 * 64 + c];
      if (t2 >= 0) fz = m[t2 * 64 + c];
      if (t3 >= 0) fw = m[t3 * 64 + c];
      s4 b = cvt4((v4f){fx, fy, fz, fw});
      v4f acc = {0.f, 0.f, 0.f, 0.f};
      acc = __builtin_amdgcn_mfma_f32_16x16x16bf16_1k(a, b, acc, 0, 0, 0);
      // D[s=q*4+r][c=h] == B-frag[k=q*4+j][n=h]  -> direct reuse as next operand
      Sfrag[le][ct] = cvt4(acc);
    }
  }

  // Oacc[mt][ub]: edges mt*16.., u = uh*32 + ub*16 + h, partial over k-half kq
  v4f Oacc[2][2];
#pragma unroll
  for (int mt = 0; mt < 2; ++mt)
#pragma unroll
    for (int ub = 0; ub < 2; ++ub) Oacc[mt][ub] = (v4f){0.f, 0.f, 0.f, 0.f};

  // rbf raw frags for ic=0 (f32, converted at use; reloaded by prefetch each ic)
  v4f Araw[LPW];
#pragma unroll
  for (int le = 0; le < LPW; ++le){
    int e = ebase + w * LPW + le; if (e >= NE) e = NE - 1;
    Araw[le] = *reinterpret_cast<const v4f*>(rbf + (size_t)e * 1024 + h * 16 + q * 4);
  }

#pragma unroll 1   // keep i-chunk loop rolled: I-cache
  for (int ic = 0; ic < 4; ++ic){
    // ---------- step 2 (transposed): mfma(Sfrag, Arbf) -> T^T tile.
    // lane(q,h) reg r = T[i=ic*16+h][c=ct*16+q*4+r] -> 4 k-contiguous -> ds_write_b64
#pragma unroll
    for (int le = 0; le < LPW; ++le){
      s4 Acvt = cvt4(Araw[le]);   // A-frag rbf: A[i=h][s=q*4+j] (as B-operand = rbf^T)
      int row = w * LPW + le;
#pragma unroll
      for (int ct = 0; ct < 4; ++ct){
        v4f acc = {0.f, 0.f, 0.f, 0.f};
        acc = __builtin_amdgcn_mfma_f32_16x16x16bf16_1k(Sfrag[le][ct], Acvt, acc, 0, 0, 0);
        s4 tv = cvt4(acc);
        // k' = (ct>>1)*512 + h*32 + (ct&1)*16 + q*4 + r ; 16B-block b = k'>>3
        int b  = (ct >> 1) * 64 + h * 4 + (ct & 1) * 2 + (q >> 1);
        int bs = b ^ (row & 7) ^ (((b >> 4) & 3) << 1);
        *reinterpret_cast<s4*>(&Tlds[row * 1024 + bs * 8 + (q & 1) * 4]) = tv;
      }
      // prefetch next ic's rbf frag; stays in flight across the raw barriers
      int icn = (ic < 3) ? ic + 1 : 3;
      int e = ebase + w * LPW + le; if (e >= NE) e = NE - 1;
      Araw[le] = *reinterpret_cast<const v4f*>(rbf + (size_t)e * 1024 + (icn * 16 + h) * 16 + q * 4);
    }
    lds_barrier();

    // ---------- step 3: Oacc += T_ic[all edges][k-half kq] @ Wb_ic[k-half][u32 slice]
    // 16 s-steps of k32; depth-4 bfr ring (F[4][2] = 32 VGPR in flight)
    const unsigned short* wp = wb + ((size_t)(ic * 128 + kq * 64 + q) * 128 + uh * 32 + h) * 8;
    s8 F[4][2];
#pragma unroll
    for (int ss = 0; ss < 4; ++ss){
      F[ss][0] = *reinterpret_cast<const s8*>(wp + ss * 4096);
      F[ss][1] = *reinterpret_cast<const s8*>(wp + ss * 4096 + 128);
    }
#pragma unroll 1
    for (int sc = 0; sc < 4; ++sc){
#pragma unroll
      for (int ss = 0; ss < 4; ++ss){
        int s = sc * 4 + ss;
        int bb = kq * 64 + s * 4 + q;
        int bsw = bb ^ (h & 7) ^ (((bb >> 4) & 3) << 1);   // rows h,16+h share (row&7==h&7)
        s8 afr0 = *reinterpret_cast<const s8*>(&Tlds[h * 1024 + bsw * 8]);
        s8 afr1 = *reinterpret_cast<const s8*>(&Tlds[(16 + h) * 1024 + bsw * 8]);
        Oacc[0][0] = __builtin_amdgcn_mfma_f32_16x16x32_bf16(afr0, F[ss][0], Oacc[0][0], 0, 0, 0);
        Oacc[1][0] = __builtin_amdgcn_mfma_f32_16x16x32_bf16(afr1, F[ss][0], Oacc[1][0], 0, 0, 0);
        Oacc[0][1] = __builtin_amdgcn_mfma_f32_16x16x32_bf16(afr0, F[ss][1], Oacc[0][1], 0, 0, 0);
        Oacc[1][1] = __builtin_amdgcn_mfma_f32_16x16x32_bf16(afr1, F[ss][1], Oacc[1][1], 0, 0, 0);
        // reload this slot for s+4 (clamped; redundant load on last chunk, harmless)
        int sn = (s + 4 < 16) ? s + 4 : s;
        F[ss][0] = *reinterpret_cast<const s8*>(wp + sn * 4096);
        F[ss][1] = *reinterpret_cast<const s8*>(wp + sn * 4096 + 128);
      }
    }
    lds_barrier();
  }

  // ---------- epilogue: pair-reduce k-halves through freed Tlds, then store.
  // kq=1 waves publish partials; kq=0 waves add and write out.
  float* red = reinterpret_cast<float*>(Tlds);   // 4 uh regions x 32e x 32u x f32 = 16 KB
  if (kq == 1){
#pragma unroll
    for (int mt = 0; mt < 2; ++mt)
#pragma unroll
      for (int ub = 0; ub < 2; ++ub)
#pragma unroll
        for (int r = 0; r < 4; ++r){
          int row = mt * 16 + q * 4 + r;
          red[uh * 1024 + row * 32 + ub * 16 + h] = Oacc[mt][ub][r];
        }
  }
  lds_barrier();
  if (kq == 0){
#pragma unroll
    for (int mt = 0; mt < 2; ++mt)
#pragma unroll
      for (int ub = 0; ub < 2; ++ub)
#pragma unroll
        for (int r = 0; r < 4; ++r){
          int row = mt * 16 + q * 4 + r;
          float v = Oacc[mt][ub][r] + red[uh * 1024 + row * 32 + ub * 16 + h];
          int e = ebase + row;
          if (e < NE) out[e * 128 + uh * 32 + ub * 16 + h] = v;
        }
  }
}

extern "C" void kernel_launch(void* const* d_in, const int* in_sizes, int n_in,
                              void* d_out, int out_size, void* d_ws, size_t ws_size,
                              hipStream_t stream) {
  const float* rbf = (const float*)d_in[0];   // (NE, 64, 16) f32
  const float* sph = (const float*)d_in[1];   // (NE, 16, 16) f32
  const float* m   = (const float*)d_in[2];   // (400000, 64) f32
  const float* wgt = (const float*)d_in[3];   // (64, 64, 128) f32
  const int* idr  = (const int*)d_in[4];      // (400000,) int32
  const int* kidx = (const int*)d_in[5];      // (400000,) int32
  float* out = (float*)d_out;                 // (NE, 128) f32

  const int nTrip = in_sizes[4];
  int*            map = (int*)d_ws;                                   // NE*16 int32 = 3.2 MB
  unsigned short* wb  = (unsigned short*)((char*)d_ws + (size_t)NE * 16 * 4); // 1 MB packed bf16 weight

  hipMemsetAsync(map, 0xFF, (size_t)NE * 16 * 4, stream);             // all slots -> -1
  scatter_map_kernel<<<dim3((nTrip + 255) / 256), dim3(256), 0, stream>>>(idr, kidx, map, nTrip);
  pack_w_kernel<<<dim3((EMB * INTERM * UOUT) / 256), dim3(256), 0, stream>>>(wgt, wb);
  fused_kernel<<<dim3((NE + EPB - 1) / EPB), dim3(512), 0, stream>>>(rbf, sph, m, wb, map, out);
}